// Round 3
// baseline (1491.182 us; speedup 1.0000x reference)
//
#include <hip/hip_runtime.h>

#define N_NODES 100000
#define N_EDGES 1600000
#define BKT 128
#define NBKT 782          // ceil(100000 / 128)
#define BKT_SHIFT 7
#define BKT_MASK 127
#define DL_SHIFT 17
#define SRC_MASK 0x1FFFF
#define CNT_BLOCKS 256
#define CVT_BLOCKS 6250   // N_NODES*64 floats / 4 / 256
#define ASTRIDE 68        // f32 row stride in LDS (64 + 4 pad -> bank rotation)

typedef __attribute__((ext_vector_type(8))) short short8;
typedef __attribute__((ext_vector_type(4))) float float4v;

__device__ __forceinline__ unsigned short f2bf(float f) {  // RNE
  unsigned u = __float_as_uint(f);
  return (unsigned short)((u + 0x7fffu + ((u >> 16) & 1u)) >> 16);
}
__device__ __forceinline__ float bflo(unsigned d) { return __uint_as_float(d << 16); }
__device__ __forceinline__ float bfhi(unsigned d) { return __uint_as_float(d & 0xffff0000u); }

// ---- K1: edge bucket count (FIRST) + weight pre-swizzle + f32->bf16 cvt ----

__global__ void k_prep_count(const float* __restrict__ in, unsigned short* __restrict__ outb,
                             const float* __restrict__ W0, const float* __restrict__ W1,
                             const float* __restrict__ W2, const float* __restrict__ W3,
                             unsigned short* __restrict__ F,
                             const int* __restrict__ dst, int* __restrict__ blkCnt) {
  __shared__ int hist[NBKT];
  const int bid = blockIdx.x;
  if (bid < CNT_BLOCKS) {
    // counting blocks dispatched first so the binning chain starts immediately
    for (int t = threadIdx.x; t < NBKT; t += 256) hist[t] = 0;
    __syncthreads();
    const int e0 = bid * (N_EDGES / CNT_BLOCKS);
    const int e1 = e0 + (N_EDGES / CNT_BLOCKS);
    for (int e = e0 + threadIdx.x; e < e1; e += 256)
      atomicAdd(&hist[dst[e] >> BKT_SHIFT], 1);
    __syncthreads();
    for (int t = threadIdx.x; t < NBKT; t += 256)
      blkCnt[t * 256 + bid] = hist[t];
    return;
  }
  if (bid < CNT_BLOCKS + 4) {
    // weight pre-swizzle into MFMA B-fragment order
    if (threadIdx.x >= 64) return;
    const int wsel = bid - CNT_BLOCKS;
    const float* W = (wsel == 0) ? W0 : (wsel == 1) ? W1 : (wsel == 2) ? W2 : W3;
    unsigned short* out = F + wsel * 4096;
    int lane = threadIdx.x;
    int col = lane & 15, kr = lane >> 4;
    #pragma unroll
    for (int kc = 0; kc < 2; kc++)
      #pragma unroll
      for (int nt = 0; nt < 4; nt++) {
        unsigned d[4];
        #pragma unroll
        for (int jj = 0; jj < 4; jj++) {
          float w0 = W[(kc * 32 + kr * 8 + 2 * jj)     * 64 + nt * 16 + col];
          float w1 = W[(kc * 32 + kr * 8 + 2 * jj + 1) * 64 + nt * 16 + col];
          d[jj] = ((unsigned)f2bf(w1) << 16) | f2bf(w0);
        }
        uint4* p = (uint4*)(out + ((kc * 4 + nt) * 64 + lane) * 8);
        *p = make_uint4(d[0], d[1], d[2], d[3]);
      }
    return;
  }
  // cvt: 6250 blocks x 256 threads x float4 == exactly N_NODES*64 floats
  int i = (bid - CNT_BLOCKS - 4) * 256 + threadIdx.x;
  float4 v = ((const float4*)in)[i];
  unsigned d0 = ((unsigned)f2bf(v.y) << 16) | f2bf(v.x);
  unsigned d1 = ((unsigned)f2bf(v.w) << 16) | f2bf(v.z);
  ((uint2*)outb)[i] = make_uint2(d0, d1);
}

// ---- K2: per-bucket scan of per-block counts -> offsets + bucket totals ----

__global__ void kA_scan1(int* __restrict__ blkCnt, int* __restrict__ bktTot) {
  const int b = blockIdx.x;
  const int tid = threadIdx.x, lane = tid & 63, w = tid >> 6;
  int v = blkCnt[b * 256 + tid];
  int inc = v;
  #pragma unroll
  for (int d = 1; d < 64; d <<= 1) { int y = __shfl_up(inc, d); if (lane >= d) inc += y; }
  __shared__ int wtot[4];
  if (lane == 63) wtot[w] = inc;
  __syncthreads();
  int base = 0;
  for (int j = 0; j < w; j++) base += wtot[j];
  blkCnt[b * 256 + tid] = base + inc - v;
  if (tid == 255) bktTot[b] = base + inc;
}

// ---- K3: scatter into bucket-grouped binned (absorbs global bucket scan) ---
// bucket starts padded to multiples of 4 edges so fused int4 reads are aligned

__global__ void kA_scatter(const int* __restrict__ src, const int* __restrict__ dst,
                           const int* __restrict__ blkCnt, const int* __restrict__ bktTot,
                           int* __restrict__ bktStart, int* __restrict__ binned) {
  __shared__ int ps[NBKT];
  __shared__ int curb[NBKT];
  const int tid = threadIdx.x;
  if (tid < 64) {
    int running = 0;
    for (int base = 0; base < NBKT; base += 64) {
      int i = base + tid;
      int v = (i < NBKT) ? bktTot[i] : 0;
      int v4 = (v + 3) & ~3;              // padded bucket size
      int inc = v4;
      #pragma unroll
      for (int d = 1; d < 64; d <<= 1) { int y = __shfl_up(inc, d); if (tid >= d) inc += y; }
      if (i < NBKT) ps[i] = running + inc - v4;
      running += __shfl(inc, 63);
    }
  }
  __syncthreads();
  for (int t = tid; t < NBKT; t += 256)
    curb[t] = ps[t] + blkCnt[t * 256 + blockIdx.x];
  if (blockIdx.x == 0)
    for (int t = tid; t < NBKT; t += 256) bktStart[t] = ps[t];
  __syncthreads();
  const int e0 = blockIdx.x * (N_EDGES / CNT_BLOCKS);
  const int e1 = e0 + (N_EDGES / CNT_BLOCKS);
  for (int e = e0 + tid; e < e1; e += 256) {
    int d = dst[e];
    int s = src[e];
    int b = d >> BKT_SHIFT;
    int p = atomicAdd(&curb[b], 1);
    binned[p] = s | ((d & BKT_MASK) << DL_SHIFT);   // src:17 | dlocal:7
  }
}

// ---- fused per-layer, bucket-resident: scatter-agg into LDS f32 -> MFMA ----
// out = self@Ws + agg@Wn + b ; no CSR, no sort: sum is order-independent.

template <bool RELU, bool OUT_BF>
__global__ __launch_bounds__(512, 4)
void k_fused(const unsigned short* __restrict__ featb, const int* __restrict__ binned,
             const int* __restrict__ bktStart, const int* __restrict__ bktTot,
             const unsigned short* __restrict__ wfS, const unsigned short* __restrict__ wfN,
             const float* __restrict__ bias,
             float* __restrict__ outf, unsigned short* __restrict__ outb) {
  __shared__ float accf[BKT * ASTRIDE];   // 34.8 KB f32 accumulator, row stride 68
  __shared__ int degs[BKT];
  const int tid = threadIdx.x;
  const int lane = tid & 63;
  const int wv = tid >> 6;                // 8 waves
  const int bkt = blockIdx.x;

  for (int i = tid; i < BKT * ASTRIDE; i += 512) accf[i] = 0.f;
  if (tid < BKT) degs[tid] = 0;
  __syncthreads();

  const int s0 = bktStart[bkt];           // 4-aligned (padded)
  const int ne = bktTot[bkt];
  const int nq = (ne + 3) >> 2;
  const int g = lane >> 3;                // 8 edge-quads per wave-iter
  const int hw = (lane & 7) * 8;          // this lane's 8-feature block
  const int h0 = (lane & 7) == 0;

  for (int qi0 = wv * 8; qi0 < nq; qi0 += 64) {
    const int qi = qi0 + g;
    if (qi < nq) {
      const int rem = ne - (qi << 2);     // >= 1
      int4 pk = *(const int4*)(binned + s0 + (qi << 2));  // aligned; pad masked below
      const int pe0 = pk.x;
      const int pe1 = (rem > 1) ? pk.y : pk.x;
      const int pe2 = (rem > 2) ? pk.z : pk.x;
      const int pe3 = (rem > 3) ? pk.w : pk.x;
      // 4 gathers in flight
      uint4 v0 = *(const uint4*)(featb + (pe0 & SRC_MASK) * 64 + hw);
      uint4 v1 = *(const uint4*)(featb + (pe1 & SRC_MASK) * 64 + hw);
      uint4 v2 = *(const uint4*)(featb + (pe2 & SRC_MASK) * 64 + hw);
      uint4 v3 = *(const uint4*)(featb + (pe3 & SRC_MASK) * 64 + hw);
      float* a0 = &accf[(pe0 >> DL_SHIFT) * ASTRIDE + hw];
      atomicAdd(a0 + 0, bflo(v0.x)); atomicAdd(a0 + 1, bfhi(v0.x));
      atomicAdd(a0 + 2, bflo(v0.y)); atomicAdd(a0 + 3, bfhi(v0.y));
      atomicAdd(a0 + 4, bflo(v0.z)); atomicAdd(a0 + 5, bfhi(v0.z));
      atomicAdd(a0 + 6, bflo(v0.w)); atomicAdd(a0 + 7, bfhi(v0.w));
      if (h0) atomicAdd(&degs[pe0 >> DL_SHIFT], 1);
      if (rem > 1) {
        float* a1 = &accf[(pe1 >> DL_SHIFT) * ASTRIDE + hw];
        atomicAdd(a1 + 0, bflo(v1.x)); atomicAdd(a1 + 1, bfhi(v1.x));
        atomicAdd(a1 + 2, bflo(v1.y)); atomicAdd(a1 + 3, bfhi(v1.y));
        atomicAdd(a1 + 4, bflo(v1.z)); atomicAdd(a1 + 5, bfhi(v1.z));
        atomicAdd(a1 + 6, bflo(v1.w)); atomicAdd(a1 + 7, bfhi(v1.w));
        if (h0) atomicAdd(&degs[pe1 >> DL_SHIFT], 1);
      }
      if (rem > 2) {
        float* a2 = &accf[(pe2 >> DL_SHIFT) * ASTRIDE + hw];
        atomicAdd(a2 + 0, bflo(v2.x)); atomicAdd(a2 + 1, bfhi(v2.x));
        atomicAdd(a2 + 2, bflo(v2.y)); atomicAdd(a2 + 3, bfhi(v2.y));
        atomicAdd(a2 + 4, bflo(v2.z)); atomicAdd(a2 + 5, bfhi(v2.z));
        atomicAdd(a2 + 6, bflo(v2.w)); atomicAdd(a2 + 7, bfhi(v2.w));
        if (h0) atomicAdd(&degs[pe2 >> DL_SHIFT], 1);
      }
      if (rem > 3) {
        float* a3 = &accf[(pe3 >> DL_SHIFT) * ASTRIDE + hw];
        atomicAdd(a3 + 0, bflo(v3.x)); atomicAdd(a3 + 1, bfhi(v3.x));
        atomicAdd(a3 + 2, bflo(v3.y)); atomicAdd(a3 + 3, bfhi(v3.y));
        atomicAdd(a3 + 4, bflo(v3.z)); atomicAdd(a3 + 5, bfhi(v3.z));
        atomicAdd(a3 + 6, bflo(v3.w)); atomicAdd(a3 + 7, bfhi(v3.w));
        if (h0) atomicAdd(&degs[pe3 >> DL_SHIFT], 1);
      }
    }
  }
  __syncthreads();

  // normalize + pack bf16 in place (XOR-swizzled 16B blocks for the MFMA read)
  {
    const int r = tid >> 2, q4 = tid & 3;       // 4 threads per row
    const int rbase = r * ASTRIDE + q4 * 16;
    const int dgv = degs[r];
    const float iv = (dgv > 0) ? (1.0f / (float)dgv) : 0.f;
    float f[16];
    #pragma unroll
    for (int j4 = 0; j4 < 4; j4++) {
      int jj = (j4 + lane) & 3;                 // bank-rotated reads
      float4 vv = *(const float4*)&accf[rbase + jj * 4];
      f[jj * 4 + 0] = vv.x * iv; f[jj * 4 + 1] = vv.y * iv;
      f[jj * 4 + 2] = vv.z * iv; f[jj * 4 + 3] = vv.w * iv;
    }
    __syncthreads();                            // all reads done before overwrite
    unsigned* au = (unsigned*)accf;
    unsigned p0 = ((unsigned)f2bf(f[1])  << 16) | f2bf(f[0]);
    unsigned p1 = ((unsigned)f2bf(f[3])  << 16) | f2bf(f[2]);
    unsigned p2 = ((unsigned)f2bf(f[5])  << 16) | f2bf(f[4]);
    unsigned p3 = ((unsigned)f2bf(f[7])  << 16) | f2bf(f[6]);
    unsigned p4 = ((unsigned)f2bf(f[9])  << 16) | f2bf(f[8]);
    unsigned p5 = ((unsigned)f2bf(f[11]) << 16) | f2bf(f[10]);
    unsigned p6 = ((unsigned)f2bf(f[13]) << 16) | f2bf(f[12]);
    unsigned p7 = ((unsigned)f2bf(f[15]) << 16) | f2bf(f[14]);
    const int wbase = r * ASTRIDE;
    const int sl0 = ((2 * q4)     ^ (r & 7)) << 2;   // word slot of 16B block
    const int sl1 = ((2 * q4 + 1) ^ (r & 7)) << 2;
    *(uint4*)&au[wbase + sl0] = make_uint4(p0, p1, p2, p3);
    *(uint4*)&au[wbase + sl1] = make_uint4(p4, p5, p6, p7);
  }
  __syncthreads();

  // ---- xform: wave wv owns the 16-node tile wv of this bucket ----
  const int tbase = bkt * BKT + wv * 16;
  if (tbase >= N_NODES) return;               // only in last bucket
  const unsigned* au = (const unsigned*)accf;
  const int col = lane & 15, rr = lane >> 4;
  const int m = tbase + col;
  short8 as0 = *(const short8*)(featb + m * 64 + rr * 8);
  short8 as1 = *(const short8*)(featb + m * 64 + 32 + rr * 8);
  const int lrow = (wv * 16 + col) * ASTRIDE;
  short8 aa0 = *(const short8*)&au[lrow + (((rr)     ^ (col & 7)) << 2)];
  short8 aa1 = *(const short8*)&au[lrow + (((rr + 4) ^ (col & 7)) << 2)];

  #pragma unroll
  for (int nt = 0; nt < 4; nt++) {
    short8 bs0 = *(const short8*)(wfS + ((0 * 4 + nt) * 64 + lane) * 8);
    short8 bs1 = *(const short8*)(wfS + ((1 * 4 + nt) * 64 + lane) * 8);
    short8 bn0 = *(const short8*)(wfN + ((0 * 4 + nt) * 64 + lane) * 8);
    short8 bn1 = *(const short8*)(wfN + ((1 * 4 + nt) * 64 + lane) * 8);
    float bvn = bias[nt * 16 + col];
    float4v cfr = {bvn, bvn, bvn, bvn};
    cfr = __builtin_amdgcn_mfma_f32_16x16x32_bf16(as0, bs0, cfr, 0, 0, 0);
    cfr = __builtin_amdgcn_mfma_f32_16x16x32_bf16(as1, bs1, cfr, 0, 0, 0);
    cfr = __builtin_amdgcn_mfma_f32_16x16x32_bf16(aa0, bn0, cfr, 0, 0, 0);
    cfr = __builtin_amdgcn_mfma_f32_16x16x32_bf16(aa1, bn1, cfr, 0, 0, 0);
    #pragma unroll
    for (int r2 = 0; r2 < 4; r2++) {
      int row = tbase + rr * 4 + r2;
      float v = cfr[r2];
      if (RELU) v = fmaxf(v, 0.f);
      if (OUT_BF) outb[row * 64 + nt * 16 + col] = f2bf(v);
      else        outf[row * 64 + nt * 16 + col] = v;
    }
  }
}

// ---- launch ----------------------------------------------------------------

extern "C" void kernel_launch(void* const* d_in, const int* in_sizes, int n_in,
                              void* d_out, int out_size, void* d_ws, size_t ws_size,
                              hipStream_t stream) {
  const float* x   = (const float*)d_in[0];
  const int*   src = (const int*)d_in[1];
  const int*   dst = (const int*)d_in[2];
  const float* Ws1 = (const float*)d_in[3];
  const float* Wn1 = (const float*)d_in[4];
  const float* b1  = (const float*)d_in[5];
  const float* Ws2 = (const float*)d_in[6];
  const float* Wn2 = (const float*)d_in[7];
  const float* b2  = (const float*)d_in[8];

  char* ws = (char*)d_ws;
  int*            blkCnt   = (int*)(ws + 0);            // NBKT*256 ints (800,768 B)
  int*            bktTot   = (int*)(ws + 802816);       // NBKT ints
  int*            bktStart = (int*)(ws + 805952);       // NBKT ints (padded starts)
  unsigned short* wf       = (unsigned short*)(ws + 809088);   // 32 KB
  int*            binned   = (int*)(ws + 841856);       // E + 4*NBKT ints (6.41 MB)
  unsigned short* xbf      = (unsigned short*)(ws + 7254400);  // N*64 bf16 (12.8 MB)
  unsigned short* hbf      = (unsigned short*)(ws + 20054400); // N*64 bf16 (12.8 MB)

  k_prep_count<<<CNT_BLOCKS + 4 + CVT_BLOCKS, 256, 0, stream>>>(
      x, xbf, Ws1, Wn1, Ws2, Wn2, wf, dst, blkCnt);
  kA_scan1<<<NBKT, 256, 0, stream>>>(blkCnt, bktTot);
  kA_scatter<<<CNT_BLOCKS, 256, 0, stream>>>(src, dst, blkCnt, bktTot, bktStart, binned);

  k_fused<true, true><<<NBKT, 512, 0, stream>>>(xbf, binned, bktStart, bktTot,
                                                wf + 0 * 4096, wf + 1 * 4096, b1,
                                                nullptr, hbf);
  k_fused<false, false><<<NBKT, 512, 0, stream>>>(hbf, binned, bktStart, bktTot,
                                                  wf + 2 * 4096, wf + 3 * 4096, b2,
                                                  (float*)d_out, nullptr);
}

// Round 4
// 381.278 us; speedup vs baseline: 3.9110x; 3.9110x over previous
//
#include <hip/hip_runtime.h>

#define N_NODES 100000
#define N_EDGES 1600000
#define NT_TILES 6250     // N_NODES / 16
#define CNT_BLOCKS 256
#define CVT_BLOCKS 6250   // N_NODES*64 floats / 4 / 256
#define SCAN_BLOCKS 196   // ceil(100000 / 512)
#define PLACE_BLOCKS 1024

typedef __attribute__((ext_vector_type(8))) short short8;
typedef __attribute__((ext_vector_type(4))) float float4v;

__device__ __forceinline__ unsigned short f2bf(float f) {  // RNE
  unsigned u = __float_as_uint(f);
  return (unsigned short)((u + 0x7fffu + ((u >> 16) & 1u)) >> 16);
}
__device__ __forceinline__ float bflo(unsigned d) { return __uint_as_float(d << 16); }
__device__ __forceinline__ float bfhi(unsigned d) { return __uint_as_float(d & 0xffff0000u); }

__device__ __forceinline__ void acc_add(float a[8], uint4 v) {
  a[0] += bflo(v.x); a[1] += bfhi(v.x);
  a[2] += bflo(v.y); a[3] += bfhi(v.y);
  a[4] += bflo(v.z); a[5] += bfhi(v.z);
  a[6] += bflo(v.w); a[7] += bfhi(v.w);
}
__device__ __forceinline__ void acc_fma(float a[8], uint4 v, float m) {
  a[0] = fmaf(m, bflo(v.x), a[0]); a[1] = fmaf(m, bfhi(v.x), a[1]);
  a[2] = fmaf(m, bflo(v.y), a[2]); a[3] = fmaf(m, bfhi(v.y), a[3]);
  a[4] = fmaf(m, bflo(v.z), a[4]); a[5] = fmaf(m, bfhi(v.z), a[5]);
  a[6] = fmaf(m, bflo(v.w), a[6]); a[7] = fmaf(m, bfhi(v.w), a[7]);
}

// ---- K1: deg count (global no-return atomics, FIRST) + wprep + cvt ---------

__global__ void k_prep_count(const float* __restrict__ in, unsigned short* __restrict__ outb,
                             const float* __restrict__ W0, const float* __restrict__ W1,
                             const float* __restrict__ W2, const float* __restrict__ W3,
                             unsigned short* __restrict__ F,
                             const int* __restrict__ dst, int* __restrict__ deg) {
  const int bid = blockIdx.x;
  if (bid < CNT_BLOCKS) {
    // no-return global atomics: fire-and-forget, fully pipelined
    const int e0 = bid * (N_EDGES / CNT_BLOCKS);
    const int e1 = e0 + (N_EDGES / CNT_BLOCKS);
    for (int e = e0 + threadIdx.x; e < e1; e += 256)
      atomicAdd(&deg[dst[e]], 1);
    return;
  }
  if (bid < CNT_BLOCKS + 4) {
    // weight pre-swizzle into MFMA B-fragment order
    if (threadIdx.x >= 64) return;
    const int wsel = bid - CNT_BLOCKS;
    const float* W = (wsel == 0) ? W0 : (wsel == 1) ? W1 : (wsel == 2) ? W2 : W3;
    unsigned short* out = F + wsel * 4096;
    int lane = threadIdx.x;
    int col = lane & 15, kr = lane >> 4;
    #pragma unroll
    for (int kc = 0; kc < 2; kc++)
      #pragma unroll
      for (int nt = 0; nt < 4; nt++) {
        unsigned d[4];
        #pragma unroll
        for (int jj = 0; jj < 4; jj++) {
          float w0 = W[(kc * 32 + kr * 8 + 2 * jj)     * 64 + nt * 16 + col];
          float w1 = W[(kc * 32 + kr * 8 + 2 * jj + 1) * 64 + nt * 16 + col];
          d[jj] = ((unsigned)f2bf(w1) << 16) | f2bf(w0);
        }
        uint4* p = (uint4*)(out + ((kc * 4 + nt) * 64 + lane) * 8);
        *p = make_uint4(d[0], d[1], d[2], d[3]);
      }
    return;
  }
  // cvt: 6250 blocks x 256 threads x float4 == exactly N_NODES*64 floats
  int i = (bid - CNT_BLOCKS - 4) * 256 + threadIdx.x;
  float4 v = ((const float4*)in)[i];
  unsigned d0 = ((unsigned)f2bf(v.y) << 16) | f2bf(v.x);
  unsigned d1 = ((unsigned)f2bf(v.w) << 16) | f2bf(v.z);
  ((uint2*)outb)[i] = make_uint2(d0, d1);
}

// ---- K2: deg -> off (exclusive scan), redundant per-block global prefix ----

__global__ __launch_bounds__(512)
void k_scan(const int* __restrict__ deg, int* __restrict__ off, int* __restrict__ cur) {
  const int b = blockIdx.x, tid = threadIdx.x, lane = tid & 63, w = tid >> 6;
  __shared__ int lds[8];
  // block prefix: sum of deg[0 .. b*512)  (L2-hot, ~39MB aggregate across grid)
  int s = 0;
  for (int i = tid; i < (b << 9); i += 512) s += deg[i];
  #pragma unroll
  for (int m = 1; m < 64; m <<= 1) s += __shfl_xor(s, m);
  if (lane == 0) lds[w] = s;
  __syncthreads();
  int bpre = 0;
  #pragma unroll
  for (int j = 0; j < 8; j++) bpre += lds[j];
  __syncthreads();
  // local scan of this block's 512 degrees
  const int n = (b << 9) + tid;
  int dv = (n < N_NODES) ? deg[n] : 0;
  int inc = dv;
  #pragma unroll
  for (int d = 1; d < 64; d <<= 1) { int y = __shfl_up(inc, d); if (lane >= d) inc += y; }
  if (lane == 63) lds[w] = inc;
  __syncthreads();
  int wpre = 0;
  for (int j = 0; j < w; j++) wpre += lds[j];
  int ex = bpre + wpre + inc - dv;
  if (n < N_NODES) { off[n] = ex; cur[n] = ex; }
  if (n == N_NODES - 1) off[N_NODES] = ex + dv;
}

// ---- K3: place edges via per-node global cursors ---------------------------

__global__ void k_place(const int* __restrict__ src, const int* __restrict__ dst,
                        int* __restrict__ cur, int* __restrict__ esrc) {
  const int chunk = (N_EDGES + PLACE_BLOCKS - 1) / PLACE_BLOCKS;
  const int e0 = blockIdx.x * chunk;
  const int e1 = min(e0 + chunk, N_EDGES);
  for (int e = e0 + threadIdx.x; e < e1; e += 256) {
    int d = dst[e];
    int s = src[e];
    int p = atomicAdd(&cur[d], 1);
    esrc[p] = s;
  }
}

// ---- fused per-layer: mean-aggregate 16 nodes -> LDS -> MFMA transform -----
// (R2-proven: 8 lanes per node, no cross-lane reduce, 4-edge unroll)

template <bool RELU, bool OUT_BF>
__global__ void k_fused(const unsigned short* __restrict__ featb,
                        const int* __restrict__ off, const int* __restrict__ esrc,
                        const unsigned short* __restrict__ wfS,
                        const unsigned short* __restrict__ wfN,
                        const float* __restrict__ bias,
                        float* __restrict__ outf, unsigned short* __restrict__ outb) {
  // per-wave 16x64 bf16 agg tile, XOR-swizzled in 16B blocks:
  // row j, block bk stored at slot bk^(j&7)
  __shared__ unsigned short aggl[4][16 * 64];
  const int tid = threadIdx.x;
  const int lane = tid & 63;
  const int wslot = tid >> 6;
  const int t = (blockIdx.x * blockDim.x + tid) >> 6;   // one 16-node tile per wave
  if (t >= NT_TILES) return;

  unsigned short* lw = &aggl[wslot][0];
  const int n = lane >> 3;   // node slot (8 nodes in parallel)
  const int h = lane & 7;    // feature block (8 bf16 = 16B), exclusive ownership

  #pragma unroll
  for (int half = 0; half < 2; ++half) {
    const int row = half * 8 + n;          // tile-local row 0..15
    const int node = t * 16 + row;
    const int o0 = off[node];
    const int o1 = off[node + 1];
    float a[8];
    #pragma unroll
    for (int q = 0; q < 8; q++) a[q] = 0.f;

    int i = o0;
    for (; i + 4 <= o1; i += 4) {          // 4 outstanding gathers per lane
      int s0 = esrc[i], s1 = esrc[i + 1], s2 = esrc[i + 2], s3 = esrc[i + 3];
      uint4 v0 = *(const uint4*)(featb + s0 * 64 + h * 8);
      uint4 v1 = *(const uint4*)(featb + s1 * 64 + h * 8);
      uint4 v2 = *(const uint4*)(featb + s2 * 64 + h * 8);
      uint4 v3 = *(const uint4*)(featb + s3 * 64 + h * 8);
      acc_add(a, v0); acc_add(a, v1); acc_add(a, v2); acc_add(a, v3);
    }
    if (i < o1) {                          // masked quad: 1..3 remaining edges
      int last = o1 - 1;
      int e1 = min(i + 1, last), e2 = min(i + 2, last);
      float m1 = (i + 1 < o1) ? 1.f : 0.f;
      float m2 = (i + 2 < o1) ? 1.f : 0.f;
      int s0 = esrc[i], s1 = esrc[e1], s2 = esrc[e2];
      uint4 v0 = *(const uint4*)(featb + s0 * 64 + h * 8);
      uint4 v1 = *(const uint4*)(featb + s1 * 64 + h * 8);
      uint4 v2 = *(const uint4*)(featb + s2 * 64 + h * 8);
      acc_add(a, v0); acc_fma(a, v1, m1); acc_fma(a, v2, m2);
    }

    const int dg = o1 - o0;
    const float inv = (dg > 0) ? (1.0f / (float)dg) : 0.f;
    unsigned d0 = ((unsigned)f2bf(a[1] * inv) << 16) | f2bf(a[0] * inv);
    unsigned d1 = ((unsigned)f2bf(a[3] * inv) << 16) | f2bf(a[2] * inv);
    unsigned d2 = ((unsigned)f2bf(a[5] * inv) << 16) | f2bf(a[4] * inv);
    unsigned d3 = ((unsigned)f2bf(a[7] * inv) << 16) | f2bf(a[6] * inv);
    *(uint4*)(lw + row * 64 + ((h ^ (row & 7)) << 3)) = make_uint4(d0, d1, d2, d3);
  }

  // same-wave LDS RAW: DS pipe is per-wave in-order; pin compiler ordering
  __builtin_amdgcn_wave_barrier();
  asm volatile("" ::: "memory");

  // ---- xform phase: 16x64 @ 64x64 via 16 MFMAs ----
  const int col = lane & 15, rr = lane >> 4;
  const int m = t * 16 + col;
  short8 as0 = *(const short8*)(featb + m * 64 + rr * 8);
  short8 as1 = *(const short8*)(featb + m * 64 + 32 + rr * 8);
  short8 aa0 = *(const short8*)(lw + col * 64 + ((rr ^ (col & 7)) << 3));
  short8 aa1 = *(const short8*)(lw + col * 64 + (((rr + 4) ^ (col & 7)) << 3));

  #pragma unroll
  for (int nt = 0; nt < 4; nt++) {
    short8 bs0 = *(const short8*)(wfS + ((0 * 4 + nt) * 64 + lane) * 8);
    short8 bs1 = *(const short8*)(wfS + ((1 * 4 + nt) * 64 + lane) * 8);
    short8 bn0 = *(const short8*)(wfN + ((0 * 4 + nt) * 64 + lane) * 8);
    short8 bn1 = *(const short8*)(wfN + ((1 * 4 + nt) * 64 + lane) * 8);
    float bvn = bias[nt * 16 + col];
    float4v cfr = {bvn, bvn, bvn, bvn};
    cfr = __builtin_amdgcn_mfma_f32_16x16x32_bf16(as0, bs0, cfr, 0, 0, 0);
    cfr = __builtin_amdgcn_mfma_f32_16x16x32_bf16(as1, bs1, cfr, 0, 0, 0);
    cfr = __builtin_amdgcn_mfma_f32_16x16x32_bf16(aa0, bn0, cfr, 0, 0, 0);
    cfr = __builtin_amdgcn_mfma_f32_16x16x32_bf16(aa1, bn1, cfr, 0, 0, 0);
    #pragma unroll
    for (int r2 = 0; r2 < 4; r2++) {
      int row = t * 16 + rr * 4 + r2;
      float v = cfr[r2];
      if (RELU) v = fmaxf(v, 0.f);
      if (OUT_BF) outb[row * 64 + nt * 16 + col] = f2bf(v);
      else        outf[row * 64 + nt * 16 + col] = v;
    }
  }
}

// ---- launch ----------------------------------------------------------------

extern "C" void kernel_launch(void* const* d_in, const int* in_sizes, int n_in,
                              void* d_out, int out_size, void* d_ws, size_t ws_size,
                              hipStream_t stream) {
  const float* x   = (const float*)d_in[0];
  const int*   src = (const int*)d_in[1];
  const int*   dst = (const int*)d_in[2];
  const float* Ws1 = (const float*)d_in[3];
  const float* Wn1 = (const float*)d_in[4];
  const float* b1  = (const float*)d_in[5];
  const float* Ws2 = (const float*)d_in[6];
  const float* Wn2 = (const float*)d_in[7];
  const float* b2  = (const float*)d_in[8];

  char* ws = (char*)d_ws;
  int*            deg  = (int*)(ws + 0);                 // N ints (400 KB)
  int*            off  = (int*)(ws + 400000);            // N+1 ints
  int*            cur  = (int*)(ws + 800064);            // N ints
  unsigned short* wf   = (unsigned short*)(ws + 1200064);   // 32 KB
  int*            esrc = (int*)(ws + 1232896);           // E ints (6.4 MB)
  unsigned short* xbf  = (unsigned short*)(ws + 7632896);   // N*64 bf16 (12.8 MB)
  unsigned short* hbf  = (unsigned short*)(ws + 20432896);  // N*64 bf16 (12.8 MB)

  hipMemsetAsync(deg, 0, N_NODES * sizeof(int), stream);

  k_prep_count<<<CNT_BLOCKS + 4 + CVT_BLOCKS, 256, 0, stream>>>(
      x, xbf, Ws1, Wn1, Ws2, Wn2, wf, dst, deg);
  k_scan<<<SCAN_BLOCKS, 512, 0, stream>>>(deg, off, cur);
  k_place<<<PLACE_BLOCKS, 256, 0, stream>>>(src, dst, cur, esrc);

  k_fused<true, true><<<1563, 256, 0, stream>>>(xbf, off, esrc, wf + 0 * 4096,
                                                wf + 1 * 4096, b1, nullptr, hbf);
  k_fused<false, false><<<1563, 256, 0, stream>>>(hbf, off, esrc, wf + 2 * 4096,
                                                  wf + 3 * 4096, b2, (float*)d_out, nullptr);
}

// Round 5
// 256.502 us; speedup vs baseline: 5.8135x; 1.4865x over previous
//
#include <hip/hip_runtime.h>

#define N_NODES 100000
#define N_EDGES 1600000
#define NBKT 196          // ceil(100000 / 512)
#define BKT_SHIFT 9
#define BKT_MASK 511
#define DL_SHIFT 17
#define SRC_MASK 0x1FFFF
#define NT_TILES 6250     // N_NODES / 16
#define CNT_BLOCKS 512    // edge chunks for count/scatter (3125 edges each)
#define CVT_BLOCKS 6250   // N_NODES*64 floats / 4 / 256

typedef __attribute__((ext_vector_type(8))) short short8;
typedef __attribute__((ext_vector_type(4))) float float4v;

__device__ __forceinline__ unsigned short f2bf(float f) {  // RNE
  unsigned u = __float_as_uint(f);
  return (unsigned short)((u + 0x7fffu + ((u >> 16) & 1u)) >> 16);
}
__device__ __forceinline__ float bflo(unsigned d) { return __uint_as_float(d << 16); }
__device__ __forceinline__ float bfhi(unsigned d) { return __uint_as_float(d & 0xffff0000u); }

__device__ __forceinline__ void acc_add(float a[8], uint4 v) {
  a[0] += bflo(v.x); a[1] += bfhi(v.x);
  a[2] += bflo(v.y); a[3] += bfhi(v.y);
  a[4] += bflo(v.z); a[5] += bfhi(v.z);
  a[6] += bflo(v.w); a[7] += bfhi(v.w);
}
__device__ __forceinline__ void acc_fma(float a[8], uint4 v, float m) {
  a[0] = fmaf(m, bflo(v.x), a[0]); a[1] = fmaf(m, bfhi(v.x), a[1]);
  a[2] = fmaf(m, bflo(v.y), a[2]); a[3] = fmaf(m, bfhi(v.y), a[3]);
  a[4] = fmaf(m, bflo(v.z), a[4]); a[5] = fmaf(m, bfhi(v.z), a[5]);
  a[6] = fmaf(m, bflo(v.w), a[6]); a[7] = fmaf(m, bfhi(v.w), a[7]);
}

// ---- K1: bucket count (LDS hist) + node degree (no-return global atomics)
//          + weight pre-swizzle + f32->bf16 cvt, one launch, count first ----

__global__ void k_prep_count(const float* __restrict__ in, unsigned short* __restrict__ outb,
                             const float* __restrict__ W0, const float* __restrict__ W1,
                             const float* __restrict__ W2, const float* __restrict__ W3,
                             unsigned short* __restrict__ F,
                             const int* __restrict__ dst,
                             int* __restrict__ blkCnt, int* __restrict__ deg) {
  __shared__ int hist[NBKT];
  const int bid = blockIdx.x;
  if (bid < CNT_BLOCKS) {
    for (int t = threadIdx.x; t < NBKT; t += 256) hist[t] = 0;
    __syncthreads();
    const int e0 = bid * (N_EDGES / CNT_BLOCKS);
    const int e1 = e0 + (N_EDGES / CNT_BLOCKS);
    for (int e = e0 + threadIdx.x; e < e1; e += 256) {
      int d = dst[e];
      atomicAdd(&hist[d >> BKT_SHIFT], 1);   // bucket hist (LDS)
      atomicAdd(&deg[d], 1);                 // node degree (global, no return use)
    }
    __syncthreads();
    for (int t = threadIdx.x; t < NBKT; t += 256)
      blkCnt[t * CNT_BLOCKS + bid] = hist[t];
    return;
  }
  if (bid < CNT_BLOCKS + 4) {
    // weight pre-swizzle into MFMA B-fragment order
    if (threadIdx.x >= 64) return;
    const int wsel = bid - CNT_BLOCKS;
    const float* W = (wsel == 0) ? W0 : (wsel == 1) ? W1 : (wsel == 2) ? W2 : W3;
    unsigned short* out = F + wsel * 4096;
    int lane = threadIdx.x;
    int col = lane & 15, kr = lane >> 4;
    #pragma unroll
    for (int kc = 0; kc < 2; kc++)
      #pragma unroll
      for (int nt = 0; nt < 4; nt++) {
        unsigned d[4];
        #pragma unroll
        for (int jj = 0; jj < 4; jj++) {
          float w0 = W[(kc * 32 + kr * 8 + 2 * jj)     * 64 + nt * 16 + col];
          float w1 = W[(kc * 32 + kr * 8 + 2 * jj + 1) * 64 + nt * 16 + col];
          d[jj] = ((unsigned)f2bf(w1) << 16) | f2bf(w0);
        }
        uint4* p = (uint4*)(out + ((kc * 4 + nt) * 64 + lane) * 8);
        *p = make_uint4(d[0], d[1], d[2], d[3]);
      }
    return;
  }
  // cvt: 6250 blocks x 256 threads x float4 == exactly N_NODES*64 floats
  int i = (bid - CNT_BLOCKS - 4) * 256 + threadIdx.x;
  float4 v = ((const float4*)in)[i];
  unsigned d0 = ((unsigned)f2bf(v.y) << 16) | f2bf(v.x);
  unsigned d1 = ((unsigned)f2bf(v.w) << 16) | f2bf(v.z);
  ((uint2*)outb)[i] = make_uint2(d0, d1);
}

// ---- K2: per-bucket exclusive scan of per-block counts + bucket totals -----

__global__ __launch_bounds__(512)
void kA_scan1(int* __restrict__ blkCnt, int* __restrict__ bktTot) {
  const int b = blockIdx.x;
  const int tid = threadIdx.x, lane = tid & 63, w = tid >> 6;
  __shared__ int wtot[8];
  int v = blkCnt[b * CNT_BLOCKS + tid];
  int inc = v;
  #pragma unroll
  for (int d = 1; d < 64; d <<= 1) { int y = __shfl_up(inc, d); if (lane >= d) inc += y; }
  if (lane == 63) wtot[w] = inc;
  __syncthreads();
  int base = 0;
  for (int j = 0; j < w; j++) base += wtot[j];
  blkCnt[b * CNT_BLOCKS + tid] = base + inc - v;
  if (tid == CNT_BLOCKS - 1) bktTot[b] = base + inc;
}

// ---- K3: scatter into bucket-grouped binned (LDS cursors, run-writes) ------

__global__ void kA_scatter(const int* __restrict__ src, const int* __restrict__ dst,
                           const int* __restrict__ blkCnt, const int* __restrict__ bktTot,
                           int* __restrict__ bktStart, int* __restrict__ binned) {
  __shared__ int ps[NBKT];
  __shared__ int curb[NBKT];
  const int tid = threadIdx.x;
  if (tid < 64) {
    int running = 0;
    for (int base = 0; base < NBKT; base += 64) {
      int i = base + tid;
      int v = (i < NBKT) ? bktTot[i] : 0;
      int inc = v;
      #pragma unroll
      for (int d = 1; d < 64; d <<= 1) { int y = __shfl_up(inc, d); if (tid >= d) inc += y; }
      if (i < NBKT) ps[i] = running + inc - v;
      running += __shfl(inc, 63);
    }
  }
  __syncthreads();
  for (int t = tid; t < NBKT; t += 256)
    curb[t] = ps[t] + blkCnt[t * CNT_BLOCKS + blockIdx.x];
  if (blockIdx.x == 0)
    for (int t = tid; t < NBKT; t += 256) bktStart[t] = ps[t];
  __syncthreads();
  const int e0 = blockIdx.x * (N_EDGES / CNT_BLOCKS);
  const int e1 = e0 + (N_EDGES / CNT_BLOCKS);
  for (int e = e0 + tid; e < e1; e += 256) {
    int d = dst[e];
    int s = src[e];
    int b = d >> BKT_SHIFT;
    int p = atomicAdd(&curb[b], 1);
    binned[p] = s | ((d & BKT_MASK) << DL_SHIFT);   // src:17 | dlocal:9
  }
}

// ---- K4: place (deg already counted -> no hist pass, one binned read) ------

__global__ __launch_bounds__(512)
void k_place(const int* __restrict__ binned, const int* __restrict__ bktStart,
             const int* __restrict__ bktTot, const int* __restrict__ deg,
             int* __restrict__ off, int* __restrict__ esrc) {
  const int b = blockIdx.x;
  const int tid = threadIdx.x, lane = tid & 63, w = tid >> 6;
  __shared__ int pos[512];
  __shared__ int wtot[8];
  const int s0 = bktStart[b];
  const int ne = bktTot[b];
  const int n = (b << BKT_SHIFT) + tid;
  int dv = (n < N_NODES) ? deg[n] : 0;
  int inc = dv;
  #pragma unroll
  for (int d = 1; d < 64; d <<= 1) { int y = __shfl_up(inc, d); if (lane >= d) inc += y; }
  if (lane == 63) wtot[w] = inc;
  __syncthreads();
  int base = s0;
  for (int j = 0; j < w; j++) base += wtot[j];
  int ex = base + inc - dv;
  pos[tid] = ex;
  if (n < N_NODES) off[n] = ex;
  if (n == N_NODES - 1) off[N_NODES] = ex + dv;
  __syncthreads();
  for (int i = tid; i < ne; i += 512) {
    int pe = binned[s0 + i];
    int p = atomicAdd(&pos[pe >> DL_SHIFT], 1);
    esrc[p] = pe & SRC_MASK;
  }
}

// ---- fused per-layer: mean-aggregate 16 nodes -> LDS -> MFMA transform -----
// (R2-proven: 8 lanes per node, no cross-lane reduce, 4-edge unroll)

template <bool RELU, bool OUT_BF>
__global__ void k_fused(const unsigned short* __restrict__ featb,
                        const int* __restrict__ off, const int* __restrict__ esrc,
                        const unsigned short* __restrict__ wfS,
                        const unsigned short* __restrict__ wfN,
                        const float* __restrict__ bias,
                        float* __restrict__ outf, unsigned short* __restrict__ outb) {
  // per-wave 16x64 bf16 agg tile, XOR-swizzled in 16B blocks:
  // row j, block bk stored at slot bk^(j&7)
  __shared__ unsigned short aggl[4][16 * 64];
  const int tid = threadIdx.x;
  const int lane = tid & 63;
  const int wslot = tid >> 6;
  const int t = (blockIdx.x * blockDim.x + tid) >> 6;   // one 16-node tile per wave
  if (t >= NT_TILES) return;

  unsigned short* lw = &aggl[wslot][0];
  const int n = lane >> 3;   // node slot (8 nodes in parallel)
  const int h = lane & 7;    // feature block (8 bf16 = 16B), exclusive ownership

  #pragma unroll
  for (int half = 0; half < 2; ++half) {
    const int row = half * 8 + n;          // tile-local row 0..15
    const int node = t * 16 + row;
    const int o0 = off[node];
    const int o1 = off[node + 1];
    float a[8];
    #pragma unroll
    for (int q = 0; q < 8; q++) a[q] = 0.f;

    int i = o0;
    for (; i + 4 <= o1; i += 4) {          // 4 outstanding gathers per lane
      int s0 = esrc[i], s1 = esrc[i + 1], s2 = esrc[i + 2], s3 = esrc[i + 3];
      uint4 v0 = *(const uint4*)(featb + s0 * 64 + h * 8);
      uint4 v1 = *(const uint4*)(featb + s1 * 64 + h * 8);
      uint4 v2 = *(const uint4*)(featb + s2 * 64 + h * 8);
      uint4 v3 = *(const uint4*)(featb + s3 * 64 + h * 8);
      acc_add(a, v0); acc_add(a, v1); acc_add(a, v2); acc_add(a, v3);
    }
    if (i < o1) {                          // masked quad: 1..3 remaining edges
      int last = o1 - 1;
      int e1 = min(i + 1, last), e2 = min(i + 2, last);
      float m1 = (i + 1 < o1) ? 1.f : 0.f;
      float m2 = (i + 2 < o1) ? 1.f : 0.f;
      int s0 = esrc[i], s1 = esrc[e1], s2 = esrc[e2];
      uint4 v0 = *(const uint4*)(featb + s0 * 64 + h * 8);
      uint4 v1 = *(const uint4*)(featb + s1 * 64 + h * 8);
      uint4 v2 = *(const uint4*)(featb + s2 * 64 + h * 8);
      acc_add(a, v0); acc_fma(a, v1, m1); acc_fma(a, v2, m2);
    }

    const int dg = o1 - o0;
    const float inv = (dg > 0) ? (1.0f / (float)dg) : 0.f;
    unsigned d0 = ((unsigned)f2bf(a[1] * inv) << 16) | f2bf(a[0] * inv);
    unsigned d1 = ((unsigned)f2bf(a[3] * inv) << 16) | f2bf(a[2] * inv);
    unsigned d2 = ((unsigned)f2bf(a[5] * inv) << 16) | f2bf(a[4] * inv);
    unsigned d3 = ((unsigned)f2bf(a[7] * inv) << 16) | f2bf(a[6] * inv);
    *(uint4*)(lw + row * 64 + ((h ^ (row & 7)) << 3)) = make_uint4(d0, d1, d2, d3);
  }

  // same-wave LDS RAW: DS pipe is per-wave in-order; pin compiler ordering
  __builtin_amdgcn_wave_barrier();
  asm volatile("" ::: "memory");

  // ---- xform phase: 16x64 @ 64x64 via 16 MFMAs ----
  const int col = lane & 15, rr = lane >> 4;
  const int m = t * 16 + col;
  short8 as0 = *(const short8*)(featb + m * 64 + rr * 8);
  short8 as1 = *(const short8*)(featb + m * 64 + 32 + rr * 8);
  short8 aa0 = *(const short8*)(lw + col * 64 + ((rr ^ (col & 7)) << 3));
  short8 aa1 = *(const short8*)(lw + col * 64 + (((rr + 4) ^ (col & 7)) << 3));

  #pragma unroll
  for (int nt = 0; nt < 4; nt++) {
    short8 bs0 = *(const short8*)(wfS + ((0 * 4 + nt) * 64 + lane) * 8);
    short8 bs1 = *(const short8*)(wfS + ((1 * 4 + nt) * 64 + lane) * 8);
    short8 bn0 = *(const short8*)(wfN + ((0 * 4 + nt) * 64 + lane) * 8);
    short8 bn1 = *(const short8*)(wfN + ((1 * 4 + nt) * 64 + lane) * 8);
    float bvn = bias[nt * 16 + col];
    float4v cfr = {bvn, bvn, bvn, bvn};
    cfr = __builtin_amdgcn_mfma_f32_16x16x32_bf16(as0, bs0, cfr, 0, 0, 0);
    cfr = __builtin_amdgcn_mfma_f32_16x16x32_bf16(as1, bs1, cfr, 0, 0, 0);
    cfr = __builtin_amdgcn_mfma_f32_16x16x32_bf16(aa0, bn0, cfr, 0, 0, 0);
    cfr = __builtin_amdgcn_mfma_f32_16x16x32_bf16(aa1, bn1, cfr, 0, 0, 0);
    #pragma unroll
    for (int r2 = 0; r2 < 4; r2++) {
      int row = t * 16 + rr * 4 + r2;
      float v = cfr[r2];
      if (RELU) v = fmaxf(v, 0.f);
      if (OUT_BF) outb[row * 64 + nt * 16 + col] = f2bf(v);
      else        outf[row * 64 + nt * 16 + col] = v;
    }
  }
}

// ---- launch ----------------------------------------------------------------

extern "C" void kernel_launch(void* const* d_in, const int* in_sizes, int n_in,
                              void* d_out, int out_size, void* d_ws, size_t ws_size,
                              hipStream_t stream) {
  const float* x   = (const float*)d_in[0];
  const int*   src = (const int*)d_in[1];
  const int*   dst = (const int*)d_in[2];
  const float* Ws1 = (const float*)d_in[3];
  const float* Wn1 = (const float*)d_in[4];
  const float* b1  = (const float*)d_in[5];
  const float* Ws2 = (const float*)d_in[6];
  const float* Wn2 = (const float*)d_in[7];
  const float* b2  = (const float*)d_in[8];

  char* ws = (char*)d_ws;
  int*            deg      = (int*)(ws + 0);              // N ints
  int*            blkCnt   = (int*)(ws + 400064);         // NBKT*512 ints
  int*            bktTot   = (int*)(ws + 801472);         // NBKT ints
  int*            bktStart = (int*)(ws + 802496);         // NBKT ints
  unsigned short* wf       = (unsigned short*)(ws + 803520);    // 32 KB
  int*            off      = (int*)(ws + 836288);         // N+1 ints
  int*            binned   = (int*)(ws + 1236352);        // E ints (6.4 MB)
  int*            esrc     = (int*)(ws + 7636352);        // E ints (6.4 MB)
  unsigned short* xbf      = (unsigned short*)(ws + 14036352);  // N*64 bf16
  unsigned short* hbf      = (unsigned short*)(ws + 26836352);  // N*64 bf16

  hipMemsetAsync(deg, 0, N_NODES * sizeof(int), stream);

  k_prep_count<<<CNT_BLOCKS + 4 + CVT_BLOCKS, 256, 0, stream>>>(
      x, xbf, Ws1, Wn1, Ws2, Wn2, wf, dst, blkCnt, deg);
  kA_scan1<<<NBKT, 512, 0, stream>>>(blkCnt, bktTot);
  kA_scatter<<<CNT_BLOCKS, 256, 0, stream>>>(src, dst, blkCnt, bktTot, bktStart, binned);
  k_place<<<NBKT, 512, 0, stream>>>(binned, bktStart, bktTot, deg, off, esrc);

  k_fused<true, true><<<1563, 256, 0, stream>>>(xbf, off, esrc, wf + 0 * 4096,
                                                wf + 1 * 4096, b1, nullptr, hbf);
  k_fused<false, false><<<1563, 256, 0, stream>>>(hbf, off, esrc, wf + 2 * 4096,
                                                  wf + 3 * 4096, b2, (float*)d_out, nullptr);
}

// Round 6
// 238.796 us; speedup vs baseline: 6.2446x; 1.0742x over previous
//
#include <hip/hip_runtime.h>

#define N_NODES 100000
#define N_EDGES 1600000
#define NBKT 392          // ceil(100000 / 256)
#define BKT_SHIFT 8
#define BKT_MASK 255
#define DL_SHIFT 17
#define SRC_MASK 0x1FFFF
#define NT_TILES 6250     // N_NODES / 16
#define CNT_BLOCKS 256
#define CVT_BLOCKS 6250   // N_NODES*64 floats / 4 / 256

typedef __attribute__((ext_vector_type(8))) short short8;
typedef __attribute__((ext_vector_type(4))) float float4v;

__device__ __forceinline__ unsigned short f2bf(float f) {  // RNE
  unsigned u = __float_as_uint(f);
  return (unsigned short)((u + 0x7fffu + ((u >> 16) & 1u)) >> 16);
}
__device__ __forceinline__ float bflo(unsigned d) { return __uint_as_float(d << 16); }
__device__ __forceinline__ float bfhi(unsigned d) { return __uint_as_float(d & 0xffff0000u); }

__device__ __forceinline__ void acc_add(float a[8], uint4 v) {
  a[0] += bflo(v.x); a[1] += bfhi(v.x);
  a[2] += bflo(v.y); a[3] += bfhi(v.y);
  a[4] += bflo(v.z); a[5] += bfhi(v.z);
  a[6] += bflo(v.w); a[7] += bfhi(v.w);
}
__device__ __forceinline__ void acc_fma(float a[8], uint4 v, float m) {
  a[0] = fmaf(m, bflo(v.x), a[0]); a[1] = fmaf(m, bfhi(v.x), a[1]);
  a[2] = fmaf(m, bflo(v.y), a[2]); a[3] = fmaf(m, bfhi(v.y), a[3]);
  a[4] = fmaf(m, bflo(v.z), a[4]); a[5] = fmaf(m, bfhi(v.z), a[5]);
  a[6] = fmaf(m, bflo(v.w), a[6]); a[7] = fmaf(m, bfhi(v.w), a[7]);
}

// ---- K1: bucket count (LDS hist, first) + weight pre-swizzle + cvt ---------

__global__ void k_prep_count(const float* __restrict__ in, unsigned short* __restrict__ outb,
                             const float* __restrict__ W0, const float* __restrict__ W1,
                             const float* __restrict__ W2, const float* __restrict__ W3,
                             unsigned short* __restrict__ F,
                             const int* __restrict__ dst, int* __restrict__ blkCnt) {
  __shared__ int hist[NBKT];
  const int bid = blockIdx.x;
  if (bid < CNT_BLOCKS) {
    for (int t = threadIdx.x; t < NBKT; t += 256) hist[t] = 0;
    __syncthreads();
    const int e0 = bid * (N_EDGES / CNT_BLOCKS);
    const int e1 = e0 + (N_EDGES / CNT_BLOCKS);
    for (int e = e0 + threadIdx.x; e < e1; e += 256)
      atomicAdd(&hist[dst[e] >> BKT_SHIFT], 1);
    __syncthreads();
    for (int t = threadIdx.x; t < NBKT; t += 256)
      blkCnt[t * CNT_BLOCKS + bid] = hist[t];
    return;
  }
  if (bid < CNT_BLOCKS + 4) {
    // weight pre-swizzle into MFMA B-fragment order
    if (threadIdx.x >= 64) return;
    const int wsel = bid - CNT_BLOCKS;
    const float* W = (wsel == 0) ? W0 : (wsel == 1) ? W1 : (wsel == 2) ? W2 : W3;
    unsigned short* out = F + wsel * 4096;
    int lane = threadIdx.x;
    int col = lane & 15, kr = lane >> 4;
    #pragma unroll
    for (int kc = 0; kc < 2; kc++)
      #pragma unroll
      for (int nt = 0; nt < 4; nt++) {
        unsigned d[4];
        #pragma unroll
        for (int jj = 0; jj < 4; jj++) {
          float w0 = W[(kc * 32 + kr * 8 + 2 * jj)     * 64 + nt * 16 + col];
          float w1 = W[(kc * 32 + kr * 8 + 2 * jj + 1) * 64 + nt * 16 + col];
          d[jj] = ((unsigned)f2bf(w1) << 16) | f2bf(w0);
        }
        uint4* p = (uint4*)(out + ((kc * 4 + nt) * 64 + lane) * 8);
        *p = make_uint4(d[0], d[1], d[2], d[3]);
      }
    return;
  }
  // cvt: 6250 blocks x 256 threads x float4 == exactly N_NODES*64 floats
  int i = (bid - CNT_BLOCKS - 4) * 256 + threadIdx.x;
  float4 v = ((const float4*)in)[i];
  unsigned d0 = ((unsigned)f2bf(v.y) << 16) | f2bf(v.x);
  unsigned d1 = ((unsigned)f2bf(v.w) << 16) | f2bf(v.z);
  ((uint2*)outb)[i] = make_uint2(d0, d1);
}

// ---- K2: per-bucket exclusive scan of per-block counts + bucket totals -----

__global__ void kA_scan1(int* __restrict__ blkCnt, int* __restrict__ bktTot) {
  const int b = blockIdx.x;
  const int tid = threadIdx.x, lane = tid & 63, w = tid >> 6;
  int v = blkCnt[b * CNT_BLOCKS + tid];
  int inc = v;
  #pragma unroll
  for (int d = 1; d < 64; d <<= 1) { int y = __shfl_up(inc, d); if (lane >= d) inc += y; }
  __shared__ int wtot[4];
  if (lane == 63) wtot[w] = inc;
  __syncthreads();
  int base = 0;
  for (int j = 0; j < w; j++) base += wtot[j];
  blkCnt[b * CNT_BLOCKS + tid] = base + inc - v;
  if (tid == CNT_BLOCKS - 1) bktTot[b] = base + inc;
}

// ---- K3: scatter into bucket-grouped binned (LDS cursors, merged ps-scan) --

__global__ void kA_scatter(const int* __restrict__ src, const int* __restrict__ dst,
                           const int* __restrict__ blkCnt, const int* __restrict__ bktTot,
                           int* __restrict__ bktStart, int* __restrict__ binned) {
  __shared__ int ps[NBKT];
  __shared__ int curb[NBKT];
  const int tid = threadIdx.x;
  if (tid < 64) {
    int running = 0;
    for (int base = 0; base < NBKT; base += 64) {
      int i = base + tid;
      int v = (i < NBKT) ? bktTot[i] : 0;
      int inc = v;
      #pragma unroll
      for (int d = 1; d < 64; d <<= 1) { int y = __shfl_up(inc, d); if (tid >= d) inc += y; }
      if (i < NBKT) ps[i] = running + inc - v;
      running += __shfl(inc, 63);
    }
  }
  __syncthreads();
  for (int t = tid; t < NBKT; t += 256)
    curb[t] = ps[t] + blkCnt[t * CNT_BLOCKS + blockIdx.x];
  if (blockIdx.x == 0)
    for (int t = tid; t < NBKT; t += 256) bktStart[t] = ps[t];
  __syncthreads();
  const int e0 = blockIdx.x * (N_EDGES / CNT_BLOCKS);
  const int e1 = e0 + (N_EDGES / CNT_BLOCKS);
  for (int e = e0 + tid; e < e1; e += 256) {
    int d = dst[e];
    int s = src[e];
    int b = d >> BKT_SHIFT;
    int p = atomicAdd(&curb[b], 1);
    binned[p] = s | ((d & BKT_MASK) << DL_SHIFT);   // src:17 | dlocal:8
  }
}

// ---- K4: merged counting sort per 256-node bucket (hist + scan + place) ----

__global__ __launch_bounds__(512)
void k_sort(const int* __restrict__ binned, const int* __restrict__ bktStart,
            const int* __restrict__ bktTot,
            int* __restrict__ off, int* __restrict__ esrc) {
  const int b = blockIdx.x;
  const int tid = threadIdx.x, lane = tid & 63, w = tid >> 6;
  __shared__ int cnt[256];
  __shared__ int pos[256];
  __shared__ int wtot[4];
  if (tid < 256) cnt[tid] = 0;
  __syncthreads();
  const int s0 = bktStart[b], ne = bktTot[b];
  for (int i = tid; i < ne; i += 512)
    atomicAdd(&cnt[binned[s0 + i] >> DL_SHIFT], 1);
  __syncthreads();
  if (tid < 256) {
    int c = cnt[tid];
    int inc = c;
    #pragma unroll
    for (int d = 1; d < 64; d <<= 1) { int y = __shfl_up(inc, d); if (lane >= d) inc += y; }
    if (lane == 63) wtot[w] = inc;
    __syncthreads();
    int base = s0;
    for (int j = 0; j < w; j++) base += wtot[j];
    int ex = base + inc - c;          // global edge offset of node (b<<8)+tid
    pos[tid] = ex;
    int n0 = (b << BKT_SHIFT) + tid;
    if (n0 < N_NODES) off[n0] = ex;
    if (n0 == N_NODES - 1) off[N_NODES] = N_EDGES;
  } else {
    __syncthreads();
  }
  __syncthreads();
  for (int i = tid; i < ne; i += 512) {
    int pe = binned[s0 + i];
    int p = atomicAdd(&pos[pe >> DL_SHIFT], 1);
    esrc[p] = pe & SRC_MASK;
  }
}

// ---- fused per-layer: mean-aggregate 16 nodes -> LDS -> MFMA transform -----
// (R2-proven structure: 8 lanes per node, no cross-lane reduce; 8-edge unroll)

template <bool RELU, bool OUT_BF>
__global__ void k_fused(const unsigned short* __restrict__ featb,
                        const int* __restrict__ off, const int* __restrict__ esrc,
                        const unsigned short* __restrict__ wfS,
                        const unsigned short* __restrict__ wfN,
                        const float* __restrict__ bias,
                        float* __restrict__ outf, unsigned short* __restrict__ outb) {
  // per-wave 16x64 bf16 agg tile, XOR-swizzled in 16B blocks:
  // row j, block bk stored at slot bk^(j&7)
  __shared__ unsigned short aggl[4][16 * 64];
  const int tid = threadIdx.x;
  const int lane = tid & 63;
  const int wslot = tid >> 6;
  const int t = (blockIdx.x * blockDim.x + tid) >> 6;   // one 16-node tile per wave
  if (t >= NT_TILES) return;

  unsigned short* lw = &aggl[wslot][0];
  const int n = lane >> 3;   // node slot (8 nodes in parallel)
  const int h = lane & 7;    // feature block (8 bf16 = 16B), exclusive ownership

  #pragma unroll
  for (int half = 0; half < 2; ++half) {
    const int row = half * 8 + n;          // tile-local row 0..15
    const int node = t * 16 + row;
    const int o0 = off[node];
    const int o1 = off[node + 1];
    float a[8];
    #pragma unroll
    for (int q = 0; q < 8; q++) a[q] = 0.f;

    int i = o0;
    for (; i + 8 <= o1; i += 8) {          // 8 outstanding gathers per lane
      int s0 = esrc[i],     s1 = esrc[i + 1], s2 = esrc[i + 2], s3 = esrc[i + 3];
      int s4 = esrc[i + 4], s5 = esrc[i + 5], s6 = esrc[i + 6], s7 = esrc[i + 7];
      uint4 v0 = *(const uint4*)(featb + s0 * 64 + h * 8);
      uint4 v1 = *(const uint4*)(featb + s1 * 64 + h * 8);
      uint4 v2 = *(const uint4*)(featb + s2 * 64 + h * 8);
      uint4 v3 = *(const uint4*)(featb + s3 * 64 + h * 8);
      uint4 v4 = *(const uint4*)(featb + s4 * 64 + h * 8);
      uint4 v5 = *(const uint4*)(featb + s5 * 64 + h * 8);
      uint4 v6 = *(const uint4*)(featb + s6 * 64 + h * 8);
      uint4 v7 = *(const uint4*)(featb + s7 * 64 + h * 8);
      acc_add(a, v0); acc_add(a, v1); acc_add(a, v2); acc_add(a, v3);
      acc_add(a, v4); acc_add(a, v5); acc_add(a, v6); acc_add(a, v7);
    }
    if (i + 4 <= o1) {
      int s0 = esrc[i], s1 = esrc[i + 1], s2 = esrc[i + 2], s3 = esrc[i + 3];
      uint4 v0 = *(const uint4*)(featb + s0 * 64 + h * 8);
      uint4 v1 = *(const uint4*)(featb + s1 * 64 + h * 8);
      uint4 v2 = *(const uint4*)(featb + s2 * 64 + h * 8);
      uint4 v3 = *(const uint4*)(featb + s3 * 64 + h * 8);
      acc_add(a, v0); acc_add(a, v1); acc_add(a, v2); acc_add(a, v3);
      i += 4;
    }
    if (i < o1) {                          // masked quad: 1..3 remaining edges
      int last = o1 - 1;
      int e1 = min(i + 1, last), e2 = min(i + 2, last);
      float m1 = (i + 1 < o1) ? 1.f : 0.f;
      float m2 = (i + 2 < o1) ? 1.f : 0.f;
      int s0 = esrc[i], s1 = esrc[e1], s2 = esrc[e2];
      uint4 v0 = *(const uint4*)(featb + s0 * 64 + h * 8);
      uint4 v1 = *(const uint4*)(featb + s1 * 64 + h * 8);
      uint4 v2 = *(const uint4*)(featb + s2 * 64 + h * 8);
      acc_add(a, v0); acc_fma(a, v1, m1); acc_fma(a, v2, m2);
    }

    const int dg = o1 - o0;
    const float inv = (dg > 0) ? (1.0f / (float)dg) : 0.f;
    unsigned d0 = ((unsigned)f2bf(a[1] * inv) << 16) | f2bf(a[0] * inv);
    unsigned d1 = ((unsigned)f2bf(a[3] * inv) << 16) | f2bf(a[2] * inv);
    unsigned d2 = ((unsigned)f2bf(a[5] * inv) << 16) | f2bf(a[4] * inv);
    unsigned d3 = ((unsigned)f2bf(a[7] * inv) << 16) | f2bf(a[6] * inv);
    *(uint4*)(lw + row * 64 + ((h ^ (row & 7)) << 3)) = make_uint4(d0, d1, d2, d3);
  }

  // same-wave LDS RAW: DS pipe is per-wave in-order; pin compiler ordering
  __builtin_amdgcn_wave_barrier();
  asm volatile("" ::: "memory");

  // ---- xform phase: 16x64 @ 64x64 via 16 MFMAs ----
  const int col = lane & 15, rr = lane >> 4;
  const int m = t * 16 + col;
  short8 as0 = *(const short8*)(featb + m * 64 + rr * 8);
  short8 as1 = *(const short8*)(featb + m * 64 + 32 + rr * 8);
  short8 aa0 = *(const short8*)(lw + col * 64 + ((rr ^ (col & 7)) << 3));
  short8 aa1 = *(const short8*)(lw + col * 64 + (((rr + 4) ^ (col & 7)) << 3));

  #pragma unroll
  for (int nt = 0; nt < 4; nt++) {
    short8 bs0 = *(const short8*)(wfS + ((0 * 4 + nt) * 64 + lane) * 8);
    short8 bs1 = *(const short8*)(wfS + ((1 * 4 + nt) * 64 + lane) * 8);
    short8 bn0 = *(const short8*)(wfN + ((0 * 4 + nt) * 64 + lane) * 8);
    short8 bn1 = *(const short8*)(wfN + ((1 * 4 + nt) * 64 + lane) * 8);
    float bvn = bias[nt * 16 + col];
    float4v cfr = {bvn, bvn, bvn, bvn};
    cfr = __builtin_amdgcn_mfma_f32_16x16x32_bf16(as0, bs0, cfr, 0, 0, 0);
    cfr = __builtin_amdgcn_mfma_f32_16x16x32_bf16(as1, bs1, cfr, 0, 0, 0);
    cfr = __builtin_amdgcn_mfma_f32_16x16x32_bf16(aa0, bn0, cfr, 0, 0, 0);
    cfr = __builtin_amdgcn_mfma_f32_16x16x32_bf16(aa1, bn1, cfr, 0, 0, 0);
    #pragma unroll
    for (int r2 = 0; r2 < 4; r2++) {
      int row = t * 16 + rr * 4 + r2;
      float v = cfr[r2];
      if (RELU) v = fmaxf(v, 0.f);
      if (OUT_BF) outb[row * 64 + nt * 16 + col] = f2bf(v);
      else        outf[row * 64 + nt * 16 + col] = v;
    }
  }
}

// ---- launch ----------------------------------------------------------------

extern "C" void kernel_launch(void* const* d_in, const int* in_sizes, int n_in,
                              void* d_out, int out_size, void* d_ws, size_t ws_size,
                              hipStream_t stream) {
  const float* x   = (const float*)d_in[0];
  const int*   src = (const int*)d_in[1];
  const int*   dst = (const int*)d_in[2];
  const float* Ws1 = (const float*)d_in[3];
  const float* Wn1 = (const float*)d_in[4];
  const float* b1  = (const float*)d_in[5];
  const float* Ws2 = (const float*)d_in[6];
  const float* Wn2 = (const float*)d_in[7];
  const float* b2  = (const float*)d_in[8];

  char* ws = (char*)d_ws;
  int*            blkCnt   = (int*)(ws + 0);              // NBKT*256 ints (401,408 B)
  int*            bktTot   = (int*)(ws + 401408);         // NBKT ints
  int*            bktStart = (int*)(ws + 403008);         // NBKT ints
  unsigned short* wf       = (unsigned short*)(ws + 404608);    // 32 KB
  int*            off      = (int*)(ws + 437376);         // N+1 ints
  int*            binned   = (int*)(ws + 837440);         // E ints (6.4 MB)
  int*            esrc     = (int*)(ws + 7237440);        // E ints (6.4 MB)
  unsigned short* xbf      = (unsigned short*)(ws + 13637440);  // N*64 bf16
  unsigned short* hbf      = (unsigned short*)(ws + 26437440);  // N*64 bf16

  k_prep_count<<<CNT_BLOCKS + 4 + CVT_BLOCKS, 256, 0, stream>>>(
      x, xbf, Ws1, Wn1, Ws2, Wn2, wf, dst, blkCnt);
  kA_scan1<<<NBKT, 256, 0, stream>>>(blkCnt, bktTot);
  kA_scatter<<<CNT_BLOCKS, 256, 0, stream>>>(src, dst, blkCnt, bktTot, bktStart, binned);
  k_sort<<<NBKT, 512, 0, stream>>>(binned, bktStart, bktTot, off, esrc);

  k_fused<true, true><<<1563, 256, 0, stream>>>(xbf, off, esrc, wf + 0 * 4096,
                                                wf + 1 * 4096, b1, nullptr, hbf);
  k_fused<false, false><<<1563, 256, 0, stream>>>(hbf, off, esrc, wf + 2 * 4096,
                                                  wf + 3 * 4096, b2, (float*)d_out, nullptr);
}

// Round 7
// 217.636 us; speedup vs baseline: 6.8517x; 1.0972x over previous
//
#include <hip/hip_runtime.h>

#define N_NODES 100000
#define N_EDGES 1600000
#define BKT 128           // nodes per bucket == nodes per fused1 block
#define NBKT 782          // ceil(100000 / 128)
#define BKT_SHIFT 7
#define BKT_MASK 127
#define DL_SHIFT 17
#define SRC_MASK 0x1FFFF
#define NT_TILES 6250     // N_NODES / 16
#define CNT_BLOCKS 128    // edge chunks for count/scatter (12500 edges each)
#define CVT_BLOCKS 1563   // 1563*256*4 float4 >= 1.6M float4
#define ESRC_CAP 3072     // per-bucket edge capacity (mean 2048, +22 sigma)

typedef __attribute__((ext_vector_type(8))) short short8;
typedef __attribute__((ext_vector_type(4))) float float4v;

__device__ __forceinline__ unsigned short f2bf(float f) {  // RNE
  unsigned u = __float_as_uint(f);
  return (unsigned short)((u + 0x7fffu + ((u >> 16) & 1u)) >> 16);
}
__device__ __forceinline__ float bflo(unsigned d) { return __uint_as_float(d << 16); }
__device__ __forceinline__ float bfhi(unsigned d) { return __uint_as_float(d & 0xffff0000u); }

__device__ __forceinline__ void acc_add(float a[8], uint4 v) {
  a[0] += bflo(v.x); a[1] += bfhi(v.x);
  a[2] += bflo(v.y); a[3] += bfhi(v.y);
  a[4] += bflo(v.z); a[5] += bfhi(v.z);
  a[6] += bflo(v.w); a[7] += bfhi(v.w);
}
__device__ __forceinline__ void acc_fma(float a[8], uint4 v, float m) {
  a[0] = fmaf(m, bflo(v.x), a[0]); a[1] = fmaf(m, bfhi(v.x), a[1]);
  a[2] = fmaf(m, bflo(v.y), a[2]); a[3] = fmaf(m, bfhi(v.y), a[3]);
  a[4] = fmaf(m, bflo(v.z), a[4]); a[5] = fmaf(m, bfhi(v.z), a[5]);
  a[6] = fmaf(m, bflo(v.w), a[6]); a[7] = fmaf(m, bfhi(v.w), a[7]);
}

// ---- K1: bucket count (LDS hist, first) + weight pre-swizzle + cvt ---------

__global__ void k_prep_count(const float* __restrict__ in, unsigned short* __restrict__ outb,
                             const float* __restrict__ W0, const float* __restrict__ W1,
                             const float* __restrict__ W2, const float* __restrict__ W3,
                             unsigned short* __restrict__ F,
                             const int* __restrict__ dst, int* __restrict__ blkCnt) {
  __shared__ int hist[NBKT];
  const int bid = blockIdx.x;
  if (bid < CNT_BLOCKS) {
    for (int t = threadIdx.x; t < NBKT; t += 256) hist[t] = 0;
    __syncthreads();
    const int e0 = bid * (N_EDGES / CNT_BLOCKS);
    const int e1 = e0 + (N_EDGES / CNT_BLOCKS);
    for (int e = e0 + threadIdx.x; e < e1; e += 256)
      atomicAdd(&hist[dst[e] >> BKT_SHIFT], 1);
    __syncthreads();
    for (int t = threadIdx.x; t < NBKT; t += 256)
      blkCnt[t * CNT_BLOCKS + bid] = hist[t];
    return;
  }
  if (bid < CNT_BLOCKS + 4) {
    // weight pre-swizzle into MFMA B-fragment order
    if (threadIdx.x >= 64) return;
    const int wsel = bid - CNT_BLOCKS;
    const float* W = (wsel == 0) ? W0 : (wsel == 1) ? W1 : (wsel == 2) ? W2 : W3;
    unsigned short* out = F + wsel * 4096;
    int lane = threadIdx.x;
    int col = lane & 15, kr = lane >> 4;
    #pragma unroll
    for (int kc = 0; kc < 2; kc++)
      #pragma unroll
      for (int nt = 0; nt < 4; nt++) {
        unsigned d[4];
        #pragma unroll
        for (int jj = 0; jj < 4; jj++) {
          float w0 = W[(kc * 32 + kr * 8 + 2 * jj)     * 64 + nt * 16 + col];
          float w1 = W[(kc * 32 + kr * 8 + 2 * jj + 1) * 64 + nt * 16 + col];
          d[jj] = ((unsigned)f2bf(w1) << 16) | f2bf(w0);
        }
        uint4* p = (uint4*)(out + ((kc * 4 + nt) * 64 + lane) * 8);
        *p = make_uint4(d[0], d[1], d[2], d[3]);
      }
    return;
  }
  // cvt: 4 float4 per thread (coalesced per sub-iter)
  const int base = (bid - CNT_BLOCKS - 4) * 1024 + threadIdx.x;
  #pragma unroll
  for (int j = 0; j < 4; j++) {
    int i = base + j * 256;
    if (i < 1600000) {
      float4 v = ((const float4*)in)[i];
      unsigned d0 = ((unsigned)f2bf(v.y) << 16) | f2bf(v.x);
      unsigned d1 = ((unsigned)f2bf(v.w) << 16) | f2bf(v.z);
      ((uint2*)outb)[i] = make_uint2(d0, d1);
    }
  }
}

// ---- K2: scatter into bucket-grouped binned (self-scan of raw blkCnt) ------

__global__ __launch_bounds__(512)
void k_scatter(const int* __restrict__ src, const int* __restrict__ dst,
               const int* __restrict__ blkCnt, int* __restrict__ bktStart,
               int* __restrict__ bktTot, int* __restrict__ binned) {
  __shared__ int totsh[NBKT];
  __shared__ int ps[NBKT];
  __shared__ int curb[NBKT];
  const int tid = threadIdx.x;
  const int bid = blockIdx.x;
  // per-bucket total + this block's within-bucket offset (raw counts, L2-hot)
  for (int t = tid; t < NBKT; t += 512) {
    const int* row = blkCnt + t * CNT_BLOCKS;
    int tot = 0, part = 0;
    #pragma unroll 4
    for (int i = 0; i < CNT_BLOCKS; i++) {
      int v = row[i];
      tot += v;
      if (i < bid) part += v;
    }
    totsh[t] = tot;
    curb[t] = part;
  }
  __syncthreads();
  // exclusive scan of bucket totals -> bucket bases
  if (tid < 64) {
    int running = 0;
    for (int base = 0; base < NBKT; base += 64) {
      int i = base + tid;
      int v = (i < NBKT) ? totsh[i] : 0;
      int inc = v;
      #pragma unroll
      for (int d = 1; d < 64; d <<= 1) { int y = __shfl_up(inc, d); if (tid >= d) inc += y; }
      if (i < NBKT) ps[i] = running + inc - v;
      running += __shfl(inc, 63);
    }
  }
  __syncthreads();
  for (int t = tid; t < NBKT; t += 512) curb[t] += ps[t];
  if (bid == 0)
    for (int t = tid; t < NBKT; t += 512) { bktStart[t] = ps[t]; bktTot[t] = totsh[t]; }
  __syncthreads();
  const int e0 = bid * (N_EDGES / CNT_BLOCKS);
  const int e1 = e0 + (N_EDGES / CNT_BLOCKS);
  for (int e = e0 + tid; e < e1; e += 512) {
    int d = dst[e];
    int s = src[e];
    int p = atomicAdd(&curb[d >> BKT_SHIFT], 1);
    binned[p] = s | ((d & BKT_MASK) << DL_SHIFT);   // src:17 | dlocal:7
  }
}

// ---- F1: layer 1 fused WITH in-block counting sort -------------------------
// block = 8 waves = one 128-node bucket: sort binned -> LDS esrc_l,
// stream sorted list + off to global (for layer 2), aggregate, MFMA xform.

__global__ __launch_bounds__(512)
void k_fused1(const unsigned short* __restrict__ featb, const int* __restrict__ binned,
              const int* __restrict__ bktStart, const int* __restrict__ bktTot,
              const unsigned short* __restrict__ wfS, const unsigned short* __restrict__ wfN,
              const float* __restrict__ bias,
              unsigned short* __restrict__ outb,
              int* __restrict__ off, int* __restrict__ esrc) {
  __shared__ int cnt[BKT];
  __shared__ int st[BKT];
  __shared__ int pos[BKT];
  __shared__ int wtot[2];
  __shared__ int esrc_l[ESRC_CAP];
  __shared__ unsigned short aggl[8][16 * 64];
  const int b = blockIdx.x;
  const int tid = threadIdx.x, lane = tid & 63;
  const int wv = tid >> 6;

  if (tid < BKT) cnt[tid] = 0;
  __syncthreads();
  const int s0 = bktStart[b], ne = bktTot[b];
  for (int i = tid; i < ne; i += 512)
    atomicAdd(&cnt[binned[s0 + i] >> DL_SHIFT], 1);
  __syncthreads();
  // scan 128 counters (2 waves of shuffles)
  int c = 0, inc = 0;
  if (tid < BKT) {
    c = cnt[tid]; inc = c;
    #pragma unroll
    for (int d = 1; d < 64; d <<= 1) { int y = __shfl_up(inc, d); if (lane >= d) inc += y; }
    if (lane == 63) wtot[tid >> 6] = inc;
  }
  __syncthreads();
  if (tid < BKT) {
    int ex = inc - c + ((tid >= 64) ? wtot[0] : 0);
    st[tid] = ex; pos[tid] = ex;
    int n0 = (b << BKT_SHIFT) + tid;
    if (n0 < N_NODES) off[n0] = s0 + ex;
    if (n0 == N_NODES - 1) off[N_NODES] = N_EDGES;
  }
  __syncthreads();
  // place into LDS edge list
  for (int i = tid; i < ne; i += 512) {
    int pe = binned[s0 + i];
    int p = atomicAdd(&pos[pe >> DL_SHIFT], 1);
    if (p < ESRC_CAP) esrc_l[p] = pe & SRC_MASK;
  }
  __syncthreads();
  // stream sorted list to global for layer 2 (coalesced)
  for (int i = tid; i < ne; i += 512) esrc[s0 + i] = esrc_l[i];

  // ---- agg: wave wv owns local rows [wv*16, wv*16+16); 8 lanes per node ----
  unsigned short* lw = &aggl[wv][0];
  const int n = lane >> 3;
  const int h = lane & 7;

  #pragma unroll
  for (int half = 0; half < 2; ++half) {
    const int row = half * 8 + n;              // 0..15
    const int lnode = wv * 16 + row;           // 0..127
    const int o0 = st[lnode];
    const int dg = cnt[lnode];
    const int o1 = o0 + dg;
    float a[8];
    #pragma unroll
    for (int q = 0; q < 8; q++) a[q] = 0.f;

    int i = o0;
    for (; i + 4 <= o1; i += 4) {
      int s0e = esrc_l[i], s1e = esrc_l[i + 1], s2e = esrc_l[i + 2], s3e = esrc_l[i + 3];
      uint4 v0 = *(const uint4*)(featb + s0e * 64 + h * 8);
      uint4 v1 = *(const uint4*)(featb + s1e * 64 + h * 8);
      uint4 v2 = *(const uint4*)(featb + s2e * 64 + h * 8);
      uint4 v3 = *(const uint4*)(featb + s3e * 64 + h * 8);
      acc_add(a, v0); acc_add(a, v1); acc_add(a, v2); acc_add(a, v3);
    }
    if (i < o1) {                               // masked quad: 1..3 remaining
      int last = o1 - 1;
      int e1 = min(i + 1, last), e2 = min(i + 2, last);
      float m1 = (i + 1 < o1) ? 1.f : 0.f;
      float m2 = (i + 2 < o1) ? 1.f : 0.f;
      int s0e = esrc_l[i], s1e = esrc_l[e1], s2e = esrc_l[e2];
      uint4 v0 = *(const uint4*)(featb + s0e * 64 + h * 8);
      uint4 v1 = *(const uint4*)(featb + s1e * 64 + h * 8);
      uint4 v2 = *(const uint4*)(featb + s2e * 64 + h * 8);
      acc_add(a, v0); acc_fma(a, v1, m1); acc_fma(a, v2, m2);
    }

    const float inv = (dg > 0) ? (1.0f / (float)dg) : 0.f;
    unsigned d0 = ((unsigned)f2bf(a[1] * inv) << 16) | f2bf(a[0] * inv);
    unsigned d1 = ((unsigned)f2bf(a[3] * inv) << 16) | f2bf(a[2] * inv);
    unsigned d2 = ((unsigned)f2bf(a[5] * inv) << 16) | f2bf(a[4] * inv);
    unsigned d3 = ((unsigned)f2bf(a[7] * inv) << 16) | f2bf(a[6] * inv);
    *(uint4*)(lw + row * 64 + ((h ^ (row & 7)) << 3)) = make_uint4(d0, d1, d2, d3);
  }

  __builtin_amdgcn_wave_barrier();
  asm volatile("" ::: "memory");

  // ---- xform: 16x64 @ 64x64 via 16 MFMAs (relu, bf16 out) ----
  const int tbase = (b << BKT_SHIFT) + wv * 16;
  if (tbase >= N_NODES) return;                 // last bucket has 32 valid nodes
  const int col = lane & 15, rr = lane >> 4;
  const int m = tbase + col;
  short8 as0 = *(const short8*)(featb + m * 64 + rr * 8);
  short8 as1 = *(const short8*)(featb + m * 64 + 32 + rr * 8);
  short8 aa0 = *(const short8*)(lw + col * 64 + ((rr ^ (col & 7)) << 3));
  short8 aa1 = *(const short8*)(lw + col * 64 + (((rr + 4) ^ (col & 7)) << 3));

  #pragma unroll
  for (int nt = 0; nt < 4; nt++) {
    short8 bs0 = *(const short8*)(wfS + ((0 * 4 + nt) * 64 + lane) * 8);
    short8 bs1 = *(const short8*)(wfS + ((1 * 4 + nt) * 64 + lane) * 8);
    short8 bn0 = *(const short8*)(wfN + ((0 * 4 + nt) * 64 + lane) * 8);
    short8 bn1 = *(const short8*)(wfN + ((1 * 4 + nt) * 64 + lane) * 8);
    float bvn = bias[nt * 16 + col];
    float4v cfr = {bvn, bvn, bvn, bvn};
    cfr = __builtin_amdgcn_mfma_f32_16x16x32_bf16(as0, bs0, cfr, 0, 0, 0);
    cfr = __builtin_amdgcn_mfma_f32_16x16x32_bf16(as1, bs1, cfr, 0, 0, 0);
    cfr = __builtin_amdgcn_mfma_f32_16x16x32_bf16(aa0, bn0, cfr, 0, 0, 0);
    cfr = __builtin_amdgcn_mfma_f32_16x16x32_bf16(aa1, bn1, cfr, 0, 0, 0);
    #pragma unroll
    for (int r2 = 0; r2 < 4; r2++) {
      int row = tbase + rr * 4 + r2;
      float v = fmaxf(cfr[r2], 0.f);
      outb[row * 64 + nt * 16 + col] = f2bf(v);
    }
  }
}

// ---- F2: layer 2 fused (R2-proven, 4-unroll, reads global off/esrc) --------

__global__ void k_fused2(const unsigned short* __restrict__ featb,
                         const int* __restrict__ off, const int* __restrict__ esrc,
                         const unsigned short* __restrict__ wfS,
                         const unsigned short* __restrict__ wfN,
                         const float* __restrict__ bias, float* __restrict__ outf) {
  __shared__ unsigned short aggl[4][16 * 64];
  const int tid = threadIdx.x;
  const int lane = tid & 63;
  const int wslot = tid >> 6;
  const int t = (blockIdx.x * blockDim.x + tid) >> 6;
  if (t >= NT_TILES) return;

  unsigned short* lw = &aggl[wslot][0];
  const int n = lane >> 3;
  const int h = lane & 7;

  #pragma unroll
  for (int half = 0; half < 2; ++half) {
    const int row = half * 8 + n;
    const int node = t * 16 + row;
    const int o0 = off[node];
    const int o1 = off[node + 1];
    float a[8];
    #pragma unroll
    for (int q = 0; q < 8; q++) a[q] = 0.f;

    int i = o0;
    for (; i + 4 <= o1; i += 4) {
      int s0 = esrc[i], s1 = esrc[i + 1], s2 = esrc[i + 2], s3 = esrc[i + 3];
      uint4 v0 = *(const uint4*)(featb + s0 * 64 + h * 8);
      uint4 v1 = *(const uint4*)(featb + s1 * 64 + h * 8);
      uint4 v2 = *(const uint4*)(featb + s2 * 64 + h * 8);
      uint4 v3 = *(const uint4*)(featb + s3 * 64 + h * 8);
      acc_add(a, v0); acc_add(a, v1); acc_add(a, v2); acc_add(a, v3);
    }
    if (i < o1) {
      int last = o1 - 1;
      int e1 = min(i + 1, last), e2 = min(i + 2, last);
      float m1 = (i + 1 < o1) ? 1.f : 0.f;
      float m2 = (i + 2 < o1) ? 1.f : 0.f;
      int s0 = esrc[i], s1 = esrc[e1], s2 = esrc[e2];
      uint4 v0 = *(const uint4*)(featb + s0 * 64 + h * 8);
      uint4 v1 = *(const uint4*)(featb + s1 * 64 + h * 8);
      uint4 v2 = *(const uint4*)(featb + s2 * 64 + h * 8);
      acc_add(a, v0); acc_fma(a, v1, m1); acc_fma(a, v2, m2);
    }

    const int dg = o1 - o0;
    const float inv = (dg > 0) ? (1.0f / (float)dg) : 0.f;
    unsigned d0 = ((unsigned)f2bf(a[1] * inv) << 16) | f2bf(a[0] * inv);
    unsigned d1 = ((unsigned)f2bf(a[3] * inv) << 16) | f2bf(a[2] * inv);
    unsigned d2 = ((unsigned)f2bf(a[5] * inv) << 16) | f2bf(a[4] * inv);
    unsigned d3 = ((unsigned)f2bf(a[7] * inv) << 16) | f2bf(a[6] * inv);
    *(uint4*)(lw + row * 64 + ((h ^ (row & 7)) << 3)) = make_uint4(d0, d1, d2, d3);
  }

  __builtin_amdgcn_wave_barrier();
  asm volatile("" ::: "memory");

  const int col = lane & 15, rr = lane >> 4;
  const int m = t * 16 + col;
  short8 as0 = *(const short8*)(featb + m * 64 + rr * 8);
  short8 as1 = *(const short8*)(featb + m * 64 + 32 + rr * 8);
  short8 aa0 = *(const short8*)(lw + col * 64 + ((rr ^ (col & 7)) << 3));
  short8 aa1 = *(const short8*)(lw + col * 64 + (((rr + 4) ^ (col & 7)) << 3));

  #pragma unroll
  for (int nt = 0; nt < 4; nt++) {
    short8 bs0 = *(const short8*)(wfS + ((0 * 4 + nt) * 64 + lane) * 8);
    short8 bs1 = *(const short8*)(wfS + ((1 * 4 + nt) * 64 + lane) * 8);
    short8 bn0 = *(const short8*)(wfN + ((0 * 4 + nt) * 64 + lane) * 8);
    short8 bn1 = *(const short8*)(wfN + ((1 * 4 + nt) * 64 + lane) * 8);
    float bvn = bias[nt * 16 + col];
    float4v cfr = {bvn, bvn, bvn, bvn};
    cfr = __builtin_amdgcn_mfma_f32_16x16x32_bf16(as0, bs0, cfr, 0, 0, 0);
    cfr = __builtin_amdgcn_mfma_f32_16x16x32_bf16(as1, bs1, cfr, 0, 0, 0);
    cfr = __builtin_amdgcn_mfma_f32_16x16x32_bf16(aa0, bn0, cfr, 0, 0, 0);
    cfr = __builtin_amdgcn_mfma_f32_16x16x32_bf16(aa1, bn1, cfr, 0, 0, 0);
    #pragma unroll
    for (int r2 = 0; r2 < 4; r2++) {
      int row = t * 16 + rr * 4 + r2;
      outf[row * 64 + nt * 16 + col] = cfr[r2];
    }
  }
}

// ---- launch ----------------------------------------------------------------

extern "C" void kernel_launch(void* const* d_in, const int* in_sizes, int n_in,
                              void* d_out, int out_size, void* d_ws, size_t ws_size,
                              hipStream_t stream) {
  const float* x   = (const float*)d_in[0];
  const int*   src = (const int*)d_in[1];
  const int*   dst = (const int*)d_in[2];
  const float* Ws1 = (const float*)d_in[3];
  const float* Wn1 = (const float*)d_in[4];
  const float* b1  = (const float*)d_in[5];
  const float* Ws2 = (const float*)d_in[6];
  const float* Wn2 = (const float*)d_in[7];
  const float* b2  = (const float*)d_in[8];

  char* ws = (char*)d_ws;
  int*            blkCnt   = (int*)(ws + 0);              // NBKT*128 ints (400,384 B)
  int*            bktTot   = (int*)(ws + 400384);         // NBKT ints
  int*            bktStart = (int*)(ws + 403512);         // NBKT ints
  unsigned short* wf       = (unsigned short*)(ws + 406656);    // 32 KB
  int*            off      = (int*)(ws + 439424);         // N+1 ints
  int*            binned   = (int*)(ws + 839680);         // E ints (6.4 MB)
  int*            esrc     = (int*)(ws + 7239680);        // E ints (6.4 MB)
  unsigned short* xbf      = (unsigned short*)(ws + 13639680);  // N*64 bf16
  unsigned short* hbf      = (unsigned short*)(ws + 26439680);  // N*64 bf16

  k_prep_count<<<CNT_BLOCKS + 4 + CVT_BLOCKS, 256, 0, stream>>>(
      x, xbf, Ws1, Wn1, Ws2, Wn2, wf, dst, blkCnt);
  k_scatter<<<CNT_BLOCKS, 512, 0, stream>>>(src, dst, blkCnt, bktStart, bktTot, binned);

  k_fused1<<<NBKT, 512, 0, stream>>>(xbf, binned, bktStart, bktTot,
                                     wf + 0 * 4096, wf + 1 * 4096, b1, hbf, off, esrc);
  k_fused2<<<1563, 256, 0, stream>>>(hbf, off, esrc, wf + 2 * 4096, wf + 3 * 4096,
                                     b2, (float*)d_out);
}